// Round 4
// baseline (345.681 us; speedup 1.0000x reference)
//
#include <hip/hip_runtime.h>
#include <stdint.h>

#define T_TOK 2048
#define D_DIM 1024
#define H_DIM 2048
#define N_EXP 8
#define MAXS  4608   // max padded slots: 4096 + 8*63 = 4600 -> 4608

// workspace layout (bytes)
#define WS_CNT    0
#define WS_BTOK   256
#define WS_BW     (WS_BTOK + N_EXP*2048*4)
#define WS_XG     (WS_BW + N_EXP*2048*4)        // 16B aligned
#define WS_HBUF   (WS_XG + (size_t)MAXS*1024*2)
#define WS_W1T    (WS_HBUF + (size_t)MAXS*2048*2)
#define WS_W2T    (WS_W1T + (size_t)N_EXP*1024*2048*2)

typedef __bf16 bf16x8 __attribute__((ext_vector_type(8)));
typedef float  f32x4  __attribute__((ext_vector_type(4)));

__device__ __forceinline__ unsigned short f2bf(float f) {
  unsigned int u = __float_as_uint(f);
  u += 0x7fffu + ((u >> 16) & 1u);   // round-to-nearest-even
  return (unsigned short)(u >> 16);
}

__device__ __forceinline__ float gelu_tanh(float x) {
  float u = 0.7978845608028654f * (x + 0.044715f * x * x * x);
  return 0.5f * x * (1.0f + tanhf(u));
}

__global__ void zero_kernel(float4* __restrict__ out4, int* __restrict__ cnt) {
  int i = blockIdx.x * 256 + threadIdx.x;  // 2048 blocks * 256 * 4 floats = T*D
  out4[i] = make_float4(0.f, 0.f, 0.f, 0.f);
  if (blockIdx.x == 0 && threadIdx.x < N_EXP) cnt[threadIdx.x] = 0;
}

// one wave per token: logits = x @ Wg + bg; top-2; softmax; bucket scatter
__global__ void gate_kernel(const float* __restrict__ x, const float* __restrict__ Wg,
                            const float* __restrict__ bg, float* __restrict__ out_idx,
                            int* __restrict__ cnt, int* __restrict__ btok,
                            float* __restrict__ bw) {
  const int lane = threadIdx.x & 63;
  const int t = blockIdx.x * 4 + (threadIdx.x >> 6);
  float p[8];
#pragma unroll
  for (int i = 0; i < 8; ++i) p[i] = 0.f;
  const float* xr = x + (size_t)t * D_DIM;
  for (int i = lane; i < D_DIM; i += 64) {
    const float xv = xr[i];
    const float4 wa = ((const float4*)(Wg + i * 8))[0];
    const float4 wb = ((const float4*)(Wg + i * 8))[1];
    p[0] += xv * wa.x; p[1] += xv * wa.y; p[2] += xv * wa.z; p[3] += xv * wa.w;
    p[4] += xv * wb.x; p[5] += xv * wb.y; p[6] += xv * wb.z; p[7] += xv * wb.w;
  }
#pragma unroll
  for (int off = 32; off > 0; off >>= 1) {
#pragma unroll
    for (int i = 0; i < 8; ++i) p[i] += __shfl_xor(p[i], off);
  }
  if (lane == 0) {
#pragma unroll
    for (int i = 0; i < 8; ++i) p[i] += bg[i];
    int i0 = 0; float v0 = p[0];
#pragma unroll
    for (int i = 1; i < 8; ++i) if (p[i] > v0) { v0 = p[i]; i0 = i; }
    int i1 = -1; float v1 = -3.4e38f;
#pragma unroll
    for (int i = 0; i < 8; ++i) if (i != i0 && p[i] > v1) { v1 = p[i]; i1 = i; }
    const float ex = expf(v1 - v0);
    const float inv = 1.f / (1.f + ex);
    out_idx[t * 2 + 0] = (float)i0;
    out_idx[t * 2 + 1] = (float)i1;
    int s0 = atomicAdd(&cnt[i0], 1);
    btok[i0 * 2048 + s0] = t; bw[i0 * 2048 + s0] = inv;
    int s1 = atomicAdd(&cnt[i1], 1);
    btok[i1 * 2048 + s1] = t; bw[i1 * 2048 + s1] = ex * inv;
  }
}

// Both weight transposes in one launch. set 0: W1 [e][1024][2048] -> [e][2048][1024]
//                                      set 1: W2 [e][2048][1024] -> [e][1024][2048]
__global__ void transpose_cvt(const float* __restrict__ W1, unsigned short* __restrict__ W1t,
                              const float* __restrict__ W2, unsigned short* __restrict__ W2t) {
  const int set = blockIdx.z;
  const int e = blockIdx.y;
  const int lin = blockIdx.x;               // 0..511
  const int R = set ? H_DIM : D_DIM;
  const int C = set ? D_DIM : H_DIM;
  const int tx = set ? (lin & 15) : (lin & 31);
  const int ty = set ? (lin >> 4) : (lin >> 5);
  const float* in = (set ? W2 : W1) + (size_t)e * (D_DIM * H_DIM);
  unsigned short* out = (set ? W2t : W1t) + (size_t)e * (D_DIM * H_DIM);
  const int c0 = tx * 64, r0 = ty * 64;
  __shared__ float tile[64][68];
  const int tid = threadIdx.x;
#pragma unroll
  for (int p = 0; p < 4; ++p) {
    const int idx = p * 256 + tid;
    const int r = idx >> 4, c4 = idx & 15;
    *(float4*)&tile[r][c4 * 4] = *(const float4*)(in + (size_t)(r0 + r) * C + c0 + c4 * 4);
  }
  __syncthreads();
#pragma unroll
  for (int p = 0; p < 2; ++p) {
    const int idx = p * 256 + tid;
    const int oc = idx >> 3, seg = idx & 7;
    unsigned u[4];
#pragma unroll
    for (int j = 0; j < 4; ++j) {
      const unsigned lo = f2bf(tile[seg * 8 + 2 * j][oc]);
      const unsigned hi = f2bf(tile[seg * 8 + 2 * j + 1][oc]);
      u[j] = lo | (hi << 16);
    }
    *(uint4*)(out + (size_t)(c0 + oc) * R + r0 + seg * 8) = make_uint4(u[0], u[1], u[2], u[3]);
  }
}

// inline padded prefix over the 8 expert counts
__device__ __forceinline__ void expert_seg(const int* __restrict__ cnt, int e,
                                           int& base, int& ce, int& pcnt) {
  int off = 0; base = 0; ce = 0; pcnt = 0;
#pragma unroll
  for (int i = 0; i < N_EXP; ++i) {
    const int c = cnt[i];
    const int p = (c + 63) & ~63;
    if (i == e) { base = off; ce = c; pcnt = p; }
    off += p;
  }
}

// one block per padded slot row: gather routed token row fp32 -> bf16 (pad rows = 0)
__global__ void gather_cvt(const float* __restrict__ x, const int* __restrict__ cnt,
                           const int* __restrict__ btok, unsigned short* __restrict__ Xg) {
  const int s = blockIdx.x;
  int off = 0, e = -1, loc = 0, c_e = 0;
#pragma unroll
  for (int i = 0; i < N_EXP; ++i) {
    const int c = cnt[i];
    const int p = (c + 63) & ~63;
    if (e < 0 && s < off + p) { e = i; loc = s - off; c_e = c; }
    off += p;
  }
  if (e < 0) return;
  uint2* orow = (uint2*)(Xg + (size_t)s * D_DIM);
  if (loc < c_e) {
    const int t = btok[e * 2048 + loc];
    const float4 v = ((const float4*)(x + (size_t)t * D_DIM))[threadIdx.x];
    uint2 u;
    u.x = (unsigned)f2bf(v.x) | ((unsigned)f2bf(v.y) << 16);
    u.y = (unsigned)f2bf(v.z) | ((unsigned)f2bf(v.w) << 16);
    orow[threadIdx.x] = u;
  } else {
    orow[threadIdx.x] = make_uint2(0u, 0u);
  }
}

// MODE 0: Hbuf[s][n] = gelu(Xg[s] @ W1t[e]^T + b1[e])     (K=1024, N=2048, SK=1)
// MODE 1: out[tok]  += w_s * (Hbuf[s] @ W2t[e]^T + b2[e]) (K=2048, N=1024, SK=2, atomic)
// 64x128 tile, BK=64, double-buffered LDS (48 KB -> 3 blocks/CU).
// LDS rows are 128 B (stride 0 mod 32 banks) -> granule rotation by (row&7),
// applied to the GLOBAL source address of global_load_lds (the DMA lane->LDS
// mapping is fixed base+lane*16) and inverted in the ds_read address. This
// spreads the 16 fragment lanes over all 8 granule positions: 2-way = free.
template <int MODE>
__global__ void __launch_bounds__(256, 3) moe_gemm(
    const unsigned short* __restrict__ A, const unsigned short* __restrict__ B,
    const float* __restrict__ bias, const int* __restrict__ cnt,
    const int* __restrict__ btok, const float* __restrict__ bw,
    unsigned short* __restrict__ Hout, float* __restrict__ out) {
  constexpr int K   = (MODE == 0) ? D_DIM : H_DIM;
  constexpr int SK  = (MODE == 0) ? 1 : 2;
  constexpr int KS  = K / SK;
  constexpr int NIT = KS / 64;

  const int lin = blockIdx.x;                 // 0..4095
  const int glo = lin & 7;
  const int mt  = (lin >> 3) & 31;            // up to 32 m-tiles of 64 rows
  const int g   = ((lin >> 8) << 3) | glo;    // 0..127
  int nt, e, ksl;
  if (MODE == 0) { nt = g & 15; e = g >> 4; ksl = 0; }
  else           { nt = g & 7;  e = (g >> 3) & 7; ksl = g >> 6; }

  int base, ce, pcnt;
  expert_seg(cnt, e, base, ce, pcnt);
  if (mt * 64 >= pcnt) return;
  const int row0 = base + mt * 64;
  const int n0 = nt * 128;

  __shared__ __align__(16) unsigned short As[2][64 * 64];
  __shared__ __align__(16) unsigned short Bs[2][128 * 64];

  const int tid = threadIdx.x;
  const int lane = tid & 63;
  const int wv = tid >> 6;
  const int wm = wv >> 1;
  const int wn = wv & 1;

  const unsigned short* Ab = A + (size_t)row0 * K + ksl * KS;
  const unsigned short* Bb = B + (size_t)e * ((size_t)H_DIM * D_DIM) + (size_t)n0 * K + ksl * KS;

  f32x4 acc[2][4];
#pragma unroll
  for (int i = 0; i < 2; ++i)
#pragma unroll
    for (int j = 0; j < 4; ++j) acc[i][j] = (f32x4)(0.0f);

  const int rloc = lane >> 3;          // 0..7 (row within 8-row chunk)
  const int q = lane & 7;              // granule slot 0..7
  const int gq = ((q - rloc) & 7) * 8; // rotated source granule (halfs)
  const int fr = lane & 15;
  const int kg = lane >> 4;            // 0..3: k-granule within 32-half MFMA window

  auto stage = [&](int kt, int b) {
    const int k0 = kt * 64;
#pragma unroll
    for (int it = 0; it < 2; ++it) {   // A: 8 chunks of 8 rows, 2 per wave
      const int ci = wv * 2 + it;
      const int r = ci * 8 + rloc;
      const unsigned short* ga = Ab + (size_t)r * K + (k0 + gq);
      __builtin_amdgcn_global_load_lds(
          (__attribute__((address_space(1))) void*)ga,
          (__attribute__((address_space(3))) void*)(As[b] + ci * 8 * 64), 16, 0, 0);
    }
#pragma unroll
    for (int it = 0; it < 4; ++it) {   // B: 16 chunks of 8 rows, 4 per wave
      const int ci = wv * 4 + it;
      const int r = ci * 8 + rloc;
      const unsigned short* gb = Bb + (size_t)r * K + (k0 + gq);
      __builtin_amdgcn_global_load_lds(
          (__attribute__((address_space(1))) void*)gb,
          (__attribute__((address_space(3))) void*)(Bs[b] + ci * 8 * 64), 16, 0, 0);
    }
  };

  stage(0, 0);
  for (int i = 0; i < NIT; ++i) {
    const int b = i & 1;
    __syncthreads();                   // drains prefetch into buf b; protects WAR on b^1
    if (i + 1 < NIT) stage(i + 1, b ^ 1);
    bf16x8 av[2][2], bv[2][4];
#pragma unroll
    for (int kk = 0; kk < 2; ++kk) {
#pragma unroll
      for (int mi = 0; mi < 2; ++mi) {
        const int rr = wm * 32 + mi * 16 + fr;
        const int slot = ((kk * 4 + kg) + (rr & 7)) & 7;
        av[kk][mi] = *(const bf16x8*)(As[b] + rr * 64 + slot * 8);
      }
#pragma unroll
      for (int ni = 0; ni < 4; ++ni) {
        const int rr = wn * 64 + ni * 16 + fr;
        const int slot = ((kk * 4 + kg) + (rr & 7)) & 7;
        bv[kk][ni] = *(const bf16x8*)(Bs[b] + rr * 64 + slot * 8);
      }
    }
#pragma unroll
    for (int kk = 0; kk < 2; ++kk)
#pragma unroll
      for (int mi = 0; mi < 2; ++mi)
#pragma unroll
        for (int ni = 0; ni < 4; ++ni)
          acc[mi][ni] = __builtin_amdgcn_mfma_f32_16x16x32_bf16(av[kk][mi], bv[kk][ni],
                                                                acc[mi][ni], 0, 0, 0);
  }

  if (MODE == 0) {
    const float* bb = bias + (size_t)e * H_DIM + n0;
#pragma unroll
    for (int mi = 0; mi < 2; ++mi) {
      const int rb = wm * 32 + mi * 16 + (lane >> 4) * 4;
#pragma unroll
      for (int r = 0; r < 4; ++r) {
        unsigned short* hp = Hout + (size_t)(row0 + rb + r) * H_DIM + n0;
#pragma unroll
        for (int ni = 0; ni < 4; ++ni) {
          const int col = wn * 64 + ni * 16 + fr;
          hp[col] = f2bf(gelu_tanh(acc[mi][ni][r] + bb[col]));
        }
      }
    }
  } else {
    const float* bb = bias + (size_t)e * D_DIM + n0;
#pragma unroll
    for (int mi = 0; mi < 2; ++mi) {
      const int rb = wm * 32 + mi * 16 + (lane >> 4) * 4;
#pragma unroll
      for (int r = 0; r < 4; ++r) {
        const int local = mt * 64 + rb + r;
        if (local < ce) {
          const int tok = btok[e * 2048 + local];
          const float w = bw[e * 2048 + local];
          float* op = out + (size_t)tok * D_DIM + n0;
#pragma unroll
          for (int ni = 0; ni < 4; ++ni) {
            const int col = wn * 64 + ni * 16 + fr;
            const float bias_once = (ksl == 0) ? bb[col] : 0.f;
            atomicAdd(op + col, w * (acc[mi][ni][r] + bias_once));
          }
        }
      }
    }
  }
}

extern "C" void kernel_launch(void* const* d_in, const int* in_sizes, int n_in,
                              void* d_out, int out_size, void* d_ws, size_t ws_size,
                              hipStream_t stream) {
  const float* moe_inp = (const float*)d_in[0];
  const float* Wg = (const float*)d_in[1];
  const float* bg = (const float*)d_in[2];
  const float* W1 = (const float*)d_in[3];
  const float* b1 = (const float*)d_in[4];
  const float* W2 = (const float*)d_in[5];
  const float* b2 = (const float*)d_in[6];
  float* out = (float*)d_out;

  char* ws = (char*)d_ws;
  int* cnt  = (int*)(ws + WS_CNT);
  int* btok = (int*)(ws + WS_BTOK);
  float* bw = (float*)(ws + WS_BW);
  unsigned short* Xg   = (unsigned short*)(ws + WS_XG);
  unsigned short* Hbuf = (unsigned short*)(ws + WS_HBUF);
  unsigned short* W1t  = (unsigned short*)(ws + WS_W1T);
  unsigned short* W2t  = (unsigned short*)(ws + WS_W2T);

  zero_kernel<<<dim3(2048), dim3(256), 0, stream>>>((float4*)out, cnt);
  gate_kernel<<<dim3(T_TOK / 4), dim3(256), 0, stream>>>(moe_inp, Wg, bg,
                                                         out + (size_t)T_TOK * D_DIM,
                                                         cnt, btok, bw);
  transpose_cvt<<<dim3(512, N_EXP, 2), dim3(256), 0, stream>>>(W1, W1t, W2, W2t);
  gather_cvt<<<dim3(MAXS), dim3(256), 0, stream>>>(moe_inp, cnt, btok, Xg);
  moe_gemm<0><<<dim3(4096), dim3(256), 0, stream>>>(
      Xg, W1t, b1, cnt, btok, bw, Hbuf, nullptr);
  moe_gemm<1><<<dim3(4096), dim3(256), 0, stream>>>(
      Hbuf, W2t, b2, cnt, btok, bw, nullptr, out);
}